// Round 2
// baseline (968.889 us; speedup 1.0000x reference)
//
#include <hip/hip_runtime.h>
#include <hip/hip_bf16.h>

// Problem: B=2, T=2048, C=2048, H=16, HD=128.
// Inputs/outputs are FLOAT32 (per reference); internal compute bf16 MFMA
// (threshold floor_eps_k=8 permits bf16 precision).

typedef __attribute__((ext_vector_type(8))) short short8;   // 8 bf16 (4 VGPRs) MFMA A/B frag
typedef __attribute__((ext_vector_type(4))) float f32x4;    // MFMA C/D frag

#define B_  2
#define T_  2048
#define C_  2048
#define H_  16
#define HD_ 128

__device__ __forceinline__ float bf2f(unsigned short u) {
  union { unsigned int i; float f; } v; v.i = ((unsigned int)u) << 16; return v.f;
}
__device__ __forceinline__ unsigned short f2bf(float f) {
  union { float f; unsigned int i; } v; v.f = f;
  unsigned int x = v.i;
  return (unsigned short)((x + 0x7fffu + ((x >> 16) & 1u)) >> 16);  // RNE
}

// ---------------------------------------------------------------------------
// NT GEMM: C[M][N] = A[M][K] * Bw[N][K]^T + bias.  128x128 tile, BK=64.
// A32/B32: source dtype is f32 (convert to bf16 while staging into LDS).
// MODE 0: f32 row-major store to Cout (ld=N)
// MODE 1: qkv scatter (bf16) — col n -> (which=n>>11, h=(n>>7)&15, d=n&127),
//         row m -> (b=m>>11, t=m&2047); dst[((b*16+h)*2048+t)*128 + d]
// MFMA 16x16x32 bf16 layouts (HW-verified, learn_hip m89/m91/m120):
//   A: lane holds A[m=lane&15][k=quad*8+j]; B: B[k=quad*8+j][n=lane&15]
//   C/D: col=lane&15, row=quad*4+reg
// LDS rows padded to 72 elems (144 B): 16B-aligned; row-to-row bank shift of
// +4 dwords -> worst 2-way aliasing on ds_read_b128 (free, m136).
// ---------------------------------------------------------------------------
template<int A32, int B32, int MODE>
__global__ __launch_bounds__(256, 2)
void gemm_nt(const void* __restrict__ Ap, const void* __restrict__ Bp,
             const float* __restrict__ bias,
             float* __restrict__ Cout,
             unsigned short* __restrict__ Qb,
             unsigned short* __restrict__ Kb,
             unsigned short* __restrict__ Vb,
             int N, int K)
{
  __shared__ unsigned short Al[128 * 72];
  __shared__ unsigned short Bl[128 * 72];
  const int tid  = threadIdx.x;
  const int wave = tid >> 6, lane = tid & 63;
  const int quad = lane >> 4, l15 = lane & 15;
  const int wm = wave >> 1, wn = wave & 1;   // 2x2 wave grid, 64x64 per wave
  const int n0 = blockIdx.x * 128, m0 = blockIdx.y * 128;

  f32x4 acc[4][4];
#pragma unroll
  for (int i = 0; i < 4; i++)
#pragma unroll
    for (int j = 0; j < 4; j++) acc[i][j] = (f32x4){0.f, 0.f, 0.f, 0.f};

  for (int k0 = 0; k0 < K; k0 += 64) {
    __syncthreads();
    // ---- stage A tile [128][64] -> Al (bf16) ----
    if constexpr (A32) {
      const float* A = (const float*)Ap;
#pragma unroll
      for (int i = 0; i < 8; i++) {            // 2048 4-elem chunks / 256 thr
        int cid = tid + i * 256;
        int r = cid >> 4, c = cid & 15;        // c: 4-float chunk
        float4 v = *(const float4*)&A[(size_t)(m0 + r) * K + k0 + c * 4];
        ushort4 h;
        h.x = f2bf(v.x); h.y = f2bf(v.y); h.z = f2bf(v.z); h.w = f2bf(v.w);
        *(ushort4*)&Al[r * 72 + c * 4] = h;    // 8B store, 8B-aligned
      }
    } else {
      const unsigned short* A = (const unsigned short*)Ap;
#pragma unroll
      for (int i = 0; i < 4; i++) {            // 1024 8-elem chunks / 256 thr
        int cid = tid + i * 256;
        int r = cid >> 3, c = cid & 7;
        *(float4*)&Al[r * 72 + c * 8] =
            *(const float4*)&A[(size_t)(m0 + r) * K + k0 + c * 8];
      }
    }
    // ---- stage B tile [128][64] -> Bl (bf16) ----
    if constexpr (B32) {
      const float* Bm = (const float*)Bp;
#pragma unroll
      for (int i = 0; i < 8; i++) {
        int cid = tid + i * 256;
        int r = cid >> 4, c = cid & 15;
        float4 v = *(const float4*)&Bm[(size_t)(n0 + r) * K + k0 + c * 4];
        ushort4 h;
        h.x = f2bf(v.x); h.y = f2bf(v.y); h.z = f2bf(v.z); h.w = f2bf(v.w);
        *(ushort4*)&Bl[r * 72 + c * 4] = h;
      }
    } else {
      const unsigned short* Bm = (const unsigned short*)Bp;
#pragma unroll
      for (int i = 0; i < 4; i++) {
        int cid = tid + i * 256;
        int r = cid >> 3, c = cid & 7;
        *(float4*)&Bl[r * 72 + c * 8] =
            *(const float4*)&Bm[(size_t)(n0 + r) * K + k0 + c * 8];
      }
    }
    __syncthreads();
#pragma unroll
    for (int kc = 0; kc < 2; kc++) {
      short8 af[4], bfr[4];
#pragma unroll
      for (int mi = 0; mi < 4; mi++)
        af[mi] = *(const short8*)&Al[(wm * 64 + mi * 16 + l15) * 72 + kc * 32 + quad * 8];
#pragma unroll
      for (int ni = 0; ni < 4; ni++)
        bfr[ni] = *(const short8*)&Bl[(wn * 64 + ni * 16 + l15) * 72 + kc * 32 + quad * 8];
#pragma unroll
      for (int mi = 0; mi < 4; mi++)
#pragma unroll
        for (int ni = 0; ni < 4; ni++)
          acc[mi][ni] = __builtin_amdgcn_mfma_f32_16x16x32_bf16(af[mi], bfr[ni], acc[mi][ni], 0, 0, 0);
    }
  }

  if constexpr (MODE == 0) {
#pragma unroll
    for (int mi = 0; mi < 4; mi++)
#pragma unroll
      for (int ni = 0; ni < 4; ni++) {
        int col = n0 + wn * 64 + ni * 16 + l15;
        float bv = bias[col];
#pragma unroll
        for (int r = 0; r < 4; r++) {
          int row = m0 + wm * 64 + mi * 16 + quad * 4 + r;
          Cout[(size_t)row * N + col] = acc[mi][ni][r] + bv;
        }
      }
  } else {
    // whole 128-wide n-block shares (which, h) since n0 is 128-aligned
    int which = n0 >> 11;
    int h = (n0 >> 7) & 15;
    unsigned short* P = (which == 0) ? Qb : (which == 1) ? Kb : Vb;
#pragma unroll
    for (int mi = 0; mi < 4; mi++)
#pragma unroll
      for (int ni = 0; ni < 4; ni++) {
        int d = wn * 64 + ni * 16 + l15;
        float bv = bias[n0 + d];
#pragma unroll
        for (int r = 0; r < 4; r++) {
          int m = m0 + wm * 64 + mi * 16 + quad * 4 + r;
          int b = m >> 11, t = m & (T_ - 1);
          P[((size_t)((b * H_ + h) * T_ + t)) * HD_ + d] = f2bf(acc[mi][ni][r] + bv);
        }
      }
  }
}

// ---------------------------------------------------------------------------
// RoPE in-place on bf16 Q and K, layout [B*H*T][128].
// Faithful to source: theta_p = 10000^(-(2**p)/128)  (2**p, not 2p!),
// positions are 1-indexed (pos = t+1). Pair (d, d+64).
// theta underflows to 0 for p >~ 11 (f32 underflow in ref too) -> identity.
// ---------------------------------------------------------------------------
__global__ void rope_k(unsigned short* __restrict__ Q, unsigned short* __restrict__ K)
{
  const int tid = threadIdx.x;
  const int w = tid >> 6, l = tid & 63;
  const int r = blockIdx.x * 4 + w;          // row over B*H*T
  const int t = r & (T_ - 1);
  const float pos = (float)(t + 1);
  const float theta = expf(-exp2f((float)l) * 0.07195578415606394f); // ln(1e4)/128
  const float ang = pos * theta;
  const float c = cosf(ang), s = sinf(ang);
  const size_t base = (size_t)r * HD_;

  float q0 = bf2f(Q[base + l]), q1 = bf2f(Q[base + l + 64]);
  Q[base + l]      = f2bf(q0 * c - q1 * s);
  Q[base + l + 64] = f2bf(q1 * c + q0 * s);
  float k0 = bf2f(K[base + l]), k1 = bf2f(K[base + l + 64]);
  K[base + l]      = f2bf(k0 * c - k1 * s);
  K[base + l + 64] = f2bf(k1 * c + k0 * s);
}

// ---------------------------------------------------------------------------
// Flash-style causal attention (bf16 in, bf16 out). 1 block = (b,h,128 q-rows);
// 4 waves x 32 rows; K-tile 64. Online-softmax state in registers (replicated
// across each 16-lane group via shfl_xor). P: C/D layout -> LDS -> A layout
// (m120-verified). V staged transposed so PV B-frags are contiguous 16B reads.
// Softmax exps are clamped (exp(min(x,0))) so non-finite values are impossible
// by construction. Output written as [B][T][H*HD] for the final GEMM.
// ---------------------------------------------------------------------------
__global__ __launch_bounds__(256, 2)
void attn_k(const unsigned short* __restrict__ Q,
            const unsigned short* __restrict__ K,
            const unsigned short* __restrict__ V,
            unsigned short* __restrict__ AO)
{
  __shared__ unsigned short Kl[64 * 136];   // K rows padded to 136 (272 B)
  __shared__ unsigned short Vt[128 * 72];   // V transposed, rows padded to 72
  __shared__ unsigned short Pl[4 * 32 * 72];// per-wave P stripe [32][72]

  const int tid  = threadIdx.x;
  const int wave = tid >> 6, lane = tid & 63;
  const int quad = lane >> 4, l15 = lane & 15;
  const int blk = blockIdx.x;
  const int qb = blk & 15, bh = blk >> 4;
  const int q0 = qb * 128;
  const unsigned short* Qh = Q + (size_t)bh * T_ * HD_;
  const unsigned short* Kh = K + (size_t)bh * T_ * HD_;
  const unsigned short* Vh = V + (size_t)bh * T_ * HD_;

  short8 qf[2][4];
#pragma unroll
  for (int mi = 0; mi < 2; mi++)
#pragma unroll
    for (int kc = 0; kc < 4; kc++)
      qf[mi][kc] = *(const short8*)&Qh[(size_t)(q0 + wave * 32 + mi * 16 + l15) * HD_ + kc * 32 + quad * 8];

  f32x4 oacc[2][8];
#pragma unroll
  for (int mi = 0; mi < 2; mi++)
#pragma unroll
    for (int n = 0; n < 8; n++) oacc[mi][n] = (f32x4){0.f, 0.f, 0.f, 0.f};
  float mst[2][4], lst[2][4];
#pragma unroll
  for (int mi = 0; mi < 2; mi++)
#pragma unroll
    for (int r = 0; r < 4; r++) { mst[mi][r] = -1e30f; lst[mi][r] = 0.f; }

  const float scale = 0.08838834764831845f;  // 1/sqrt(128)
  const int ktend = q0 + 128;

  for (int kt = 0; kt < ktend; kt += 64) {
    __syncthreads();
#pragma unroll
    for (int i = 0; i < 4; i++) {
      int cid = tid + i * 256;
      int r = cid >> 4, c = cid & 15;
      *(float4*)&Kl[r * 136 + c * 8] =
          *(const float4*)&Kh[(size_t)(kt + r) * HD_ + c * 8];
    }
#pragma unroll
    for (int i = 0; i < 4; i++) {
      int cid = tid + i * 256;
      int r = cid >> 4, c = cid & 15;
      const unsigned short* src = &Vh[(size_t)(kt + r) * HD_ + c * 8];
#pragma unroll
      for (int j = 0; j < 8; j++) Vt[(c * 8 + j) * 72 + r] = src[j];
    }
    __syncthreads();

    f32x4 sa[2][4];
#pragma unroll
    for (int mi = 0; mi < 2; mi++)
#pragma unroll
      for (int ni = 0; ni < 4; ni++) sa[mi][ni] = (f32x4){0.f, 0.f, 0.f, 0.f};
#pragma unroll
    for (int kc = 0; kc < 4; kc++) {
      short8 bfr[4];
#pragma unroll
      for (int ni = 0; ni < 4; ni++)
        bfr[ni] = *(const short8*)&Kl[(ni * 16 + l15) * 136 + kc * 32 + quad * 8];
#pragma unroll
      for (int mi = 0; mi < 2; mi++)
#pragma unroll
        for (int ni = 0; ni < 4; ni++)
          sa[mi][ni] = __builtin_amdgcn_mfma_f32_16x16x32_bf16(qf[mi][kc], bfr[ni], sa[mi][ni], 0, 0, 0);
    }

#pragma unroll
    for (int mi = 0; mi < 2; mi++) {
      float rmax[4];
#pragma unroll
      for (int r = 0; r < 4; r++) rmax[r] = -1e30f;
#pragma unroll
      for (int ni = 0; ni < 4; ni++) {
        int gcol = kt + ni * 16 + l15;
#pragma unroll
        for (int r = 0; r < 4; r++) {
          int grow = q0 + wave * 32 + mi * 16 + quad * 4 + r;
          float v = sa[mi][ni][r] * scale;
          v = (gcol > grow) ? -1e30f : v;   // causal mask (finite)
          sa[mi][ni][r] = v;
          rmax[r] = fmaxf(rmax[r], v);
        }
      }
#pragma unroll
      for (int r = 0; r < 4; r++)
#pragma unroll
        for (int off = 1; off < 16; off <<= 1)
          rmax[r] = fmaxf(rmax[r], __shfl_xor(rmax[r], off));
      float alpha[4];
#pragma unroll
      for (int r = 0; r < 4; r++) {
        float mnew = fmaxf(mst[mi][r], rmax[r]);
        alpha[r] = __expf(fminf(mst[mi][r] - mnew, 0.f));
        mst[mi][r] = mnew;
      }
      float rsum[4] = {0.f, 0.f, 0.f, 0.f};
#pragma unroll
      for (int ni = 0; ni < 4; ni++)
#pragma unroll
        for (int r = 0; r < 4; r++) {
          float p = __expf(fminf(sa[mi][ni][r] - mst[mi][r], 0.f));
          sa[mi][ni][r] = p;
          rsum[r] += p;
        }
#pragma unroll
      for (int r = 0; r < 4; r++) {
#pragma unroll
        for (int off = 1; off < 16; off <<= 1)
          rsum[r] += __shfl_xor(rsum[r], off);
        lst[mi][r] = lst[mi][r] * alpha[r] + rsum[r];
      }
#pragma unroll
      for (int nv = 0; nv < 8; nv++)
#pragma unroll
        for (int r = 0; r < 4; r++) oacc[mi][nv][r] *= alpha[r];
#pragma unroll
      for (int ni = 0; ni < 4; ni++)
#pragma unroll
        for (int r = 0; r < 4; r++)
          Pl[wave * 32 * 72 + (mi * 16 + quad * 4 + r) * 72 + ni * 16 + l15] = f2bf(sa[mi][ni][r]);
    }
    __syncthreads();

    short8 pf[2][2];
#pragma unroll
    for (int mi = 0; mi < 2; mi++)
#pragma unroll
      for (int kc = 0; kc < 2; kc++)
        pf[mi][kc] = *(const short8*)&Pl[wave * 32 * 72 + (mi * 16 + l15) * 72 + kc * 32 + quad * 8];
#pragma unroll
    for (int nv = 0; nv < 8; nv++)
#pragma unroll
      for (int kc = 0; kc < 2; kc++) {
        short8 vb = *(const short8*)&Vt[(nv * 16 + l15) * 72 + kc * 32 + quad * 8];
#pragma unroll
        for (int mi = 0; mi < 2; mi++)
          oacc[mi][nv] = __builtin_amdgcn_mfma_f32_16x16x32_bf16(pf[mi][kc], vb, oacc[mi][nv], 0, 0, 0);
      }
  }

  const int b = bh >> 4, h = bh & 15;
#pragma unroll
  for (int mi = 0; mi < 2; mi++) {
    float linv[4];
#pragma unroll
    for (int r = 0; r < 4; r++) linv[r] = 1.0f / fmaxf(lst[mi][r], 1e-20f);
#pragma unroll
    for (int nv = 0; nv < 8; nv++)
#pragma unroll
      for (int r = 0; r < 4; r++) {
        int t = q0 + wave * 32 + mi * 16 + quad * 4 + r;
        int d = nv * 16 + l15;
        AO[((size_t)(b * T_ + t)) * C_ + h * HD_ + d] = f2bf(oacc[mi][nv][r] * linv[r]);
      }
  }
}

// ---------------------------------------------------------------------------
extern "C" void kernel_launch(void* const* d_in, const int* in_sizes, int n_in,
                              void* d_out, int out_size, void* d_ws, size_t ws_size,
                              hipStream_t stream)
{
  const float* x    = (const float*)d_in[0];  // [2,2048,2048] f32
  const float* Wqkv = (const float*)d_in[1];  // [6144,2048]   f32
  const float* bqkv = (const float*)d_in[2];  // [6144]        f32
  const float* Wo   = (const float*)d_in[3];  // [2048,2048]   f32
  const float* bo   = (const float*)d_in[4];  // [2048]        f32
  float* out = (float*)d_out;                 // [2,2048,2048] f32

  // workspace (bf16): Q,K,V [B,H,T,HD] + AO [B*T,C] = 4 x 16 MB = 64 MB
  const size_t SZ = (size_t)B_ * H_ * T_ * HD_;
  unsigned short* ws = (unsigned short*)d_ws;
  unsigned short* Qb = ws;
  unsigned short* Kb = Qb + SZ;
  unsigned short* Vb = Kb + SZ;
  unsigned short* AO = Vb + SZ;

  dim3 blk(256, 1, 1);
  // 1) QKV GEMM (f32 in, bf16 scatter into head-major Q/K/V)
  gemm_nt<1, 1, 1><<<dim3(48, 32, 1), blk, 0, stream>>>(
      (const void*)x, (const void*)Wqkv, bqkv, nullptr, Qb, Kb, Vb, 6144, 2048);
  // 2) RoPE in-place on Q, K
  rope_k<<<dim3((B_ * H_ * T_) / 4, 1, 1), blk, 0, stream>>>(Qb, Kb);
  // 3) causal flash attention -> AO [4096][2048] bf16
  attn_k<<<dim3(512, 1, 1), blk, 0, stream>>>(Qb, Kb, Vb, AO);
  // 4) output projection (bf16 A, f32 B, f32 out)
  gemm_nt<0, 1, 0><<<dim3(16, 32, 1), blk, 0, stream>>>(
      (const void*)AO, (const void*)Wo, bo, out, nullptr, nullptr, nullptr, 2048, 2048);
}

// Round 3
// 570.721 us; speedup vs baseline: 1.6977x; 1.6977x over previous
//
#include <hip/hip_runtime.h>
#include <hip/hip_bf16.h>

// Problem: B=2, T=2048, C=2048, H=16, HD=128.
// Inputs/outputs FLOAT32 (per reference); internal compute bf16 MFMA.
// Round 3: pre-convert inputs to bf16 once, then m97-style GEMMs with
// global_load_lds width=16 async staging (874 TF structure, learn_hip m97).
// Attention/rope kept byte-identical to the round-2 passing version.

typedef __attribute__((ext_vector_type(8))) short short8;   // 8 bf16 MFMA A/B frag
typedef __attribute__((ext_vector_type(4))) float f32x4;    // MFMA C/D frag

#define B_  2
#define T_  2048
#define C_  2048
#define H_  16
#define HD_ 128

__device__ __forceinline__ float bf2f(unsigned short u) {
  union { unsigned int i; float f; } v; v.i = ((unsigned int)u) << 16; return v.f;
}
__device__ __forceinline__ unsigned short f2bf(float f) {
  union { float f; unsigned int i; } v; v.f = f;
  unsigned int x = v.i;
  return (unsigned short)((x + 0x7fffu + ((x >> 16) & 1u)) >> 16);  // RNE
}

// async 16B global->LDS copy; lds base must be wave-uniform, lane l lands at
// base + l*16 (m97/m104 semantics).
__device__ __forceinline__ void gll16(const unsigned short* g, unsigned short* lds_base) {
  __builtin_amdgcn_global_load_lds(
      (const __attribute__((address_space(1))) void*)g,
      (__attribute__((address_space(3))) void*)lds_base, 16, 0, 0);
}

// ---------------------------------------------------------------------------
// f32 -> bf16 elementwise convert, 4 elems/thread.
// ---------------------------------------------------------------------------
__global__ void cvt_k(const float* __restrict__ src, unsigned short* __restrict__ dst, int n4)
{
  int i = blockIdx.x * blockDim.x + threadIdx.x;
  if (i < n4) {
    float4 v = ((const float4*)src)[i];
    ushort4 h;
    h.x = f2bf(v.x); h.y = f2bf(v.y); h.z = f2bf(v.z); h.w = f2bf(v.w);
    ((ushort4*)dst)[i] = h;
  }
}

// ---------------------------------------------------------------------------
// m97-style NT GEMM (bf16 x bf16): C[M][N] = A[M][K]*Bw[N][K]^T + bias.
// 128x128 tile, BK=64, 2x2 waves of 64x64, 4x4 16x16x32 MFMA frags.
// Staging: global_load_lds width=16, unpadded LDS [128][64] (required by the
// wave-uniform-base + lane*16 LDS landing pattern; chunk c -> LDS byte c*16
// == row-major (c>>3)*128 + (c&7)*16, exactly the lane order). Accepts the
// m97 bank aliasing on ds_read_b128 (874 TF measured with this layout).
// MODE 0: f32 row-major store. MODE 1: bf16 qkv scatter
//   col n -> (which=n>>11, h=(n>>7)&15, d=n&127); row m -> (b=m>>11, t=m&2047)
// MFMA layouts (HW-verified m89/m91): A: A[m=lane&15][k=quad*8+j];
// B: B[k=quad*8+j][n=lane&15]; C/D: col=lane&15, row=quad*4+reg.
// ---------------------------------------------------------------------------
template<int MODE>
__global__ __launch_bounds__(256, 2)
void gemm_bt(const unsigned short* __restrict__ A,
             const unsigned short* __restrict__ Bw,
             const float* __restrict__ bias,
             float* __restrict__ Cout,
             unsigned short* __restrict__ Qb,
             unsigned short* __restrict__ Kb,
             unsigned short* __restrict__ Vb,
             int N, int K)
{
  __shared__ unsigned short Al[128 * 64];
  __shared__ unsigned short Bl[128 * 64];
  const int tid  = threadIdx.x;
  const int wave = tid >> 6, lane = tid & 63;
  const int quad = lane >> 4, l15 = lane & 15;
  const int wm = wave >> 1, wn = wave & 1;
  const int n0 = blockIdx.x * 128, m0 = blockIdx.y * 128;

  f32x4 acc[4][4];
#pragma unroll
  for (int i = 0; i < 4; i++)
#pragma unroll
    for (int j = 0; j < 4; j++) acc[i][j] = (f32x4){0.f, 0.f, 0.f, 0.f};

  for (int k0 = 0; k0 < K; k0 += 64) {
    __syncthreads();   // prior ds_reads done before overwriting LDS
    const unsigned short* Ag = A + (size_t)m0 * K + k0;
    const unsigned short* Bg = Bw + (size_t)n0 * K + k0;
#pragma unroll
    for (int i = 0; i < 4; i++) {
      int cc = i * 256 + wave * 64 + lane;      // 16B chunk id, 0..1023
      int r = cc >> 3, c8 = cc & 7;
      gll16(Ag + (size_t)r * K + c8 * 8, &Al[(i * 4 + wave) * 512]);
      gll16(Bg + (size_t)r * K + c8 * 8, &Bl[(i * 4 + wave) * 512]);
    }
    __syncthreads();   // compiler drains vmcnt(0) before barrier -> LDS valid
#pragma unroll
    for (int kc = 0; kc < 2; kc++) {
      short8 af[4], bfr[4];
#pragma unroll
      for (int mi = 0; mi < 4; mi++)
        af[mi] = *(const short8*)&Al[(wm * 64 + mi * 16 + l15) * 64 + kc * 32 + quad * 8];
#pragma unroll
      for (int ni = 0; ni < 4; ni++)
        bfr[ni] = *(const short8*)&Bl[(wn * 64 + ni * 16 + l15) * 64 + kc * 32 + quad * 8];
#pragma unroll
      for (int mi = 0; mi < 4; mi++)
#pragma unroll
        for (int ni = 0; ni < 4; ni++)
          acc[mi][ni] = __builtin_amdgcn_mfma_f32_16x16x32_bf16(af[mi], bfr[ni], acc[mi][ni], 0, 0, 0);
    }
  }

  if constexpr (MODE == 0) {
#pragma unroll
    for (int mi = 0; mi < 4; mi++)
#pragma unroll
      for (int ni = 0; ni < 4; ni++) {
        int col = n0 + wn * 64 + ni * 16 + l15;
        float bv = bias[col];
#pragma unroll
        for (int r = 0; r < 4; r++) {
          int row = m0 + wm * 64 + mi * 16 + quad * 4 + r;
          Cout[(size_t)row * N + col] = acc[mi][ni][r] + bv;
        }
      }
  } else {
    int which = n0 >> 11;
    int h = (n0 >> 7) & 15;
    unsigned short* P = (which == 0) ? Qb : (which == 1) ? Kb : Vb;
#pragma unroll
    for (int mi = 0; mi < 4; mi++)
#pragma unroll
      for (int ni = 0; ni < 4; ni++) {
        int d = wn * 64 + ni * 16 + l15;
        float bv = bias[n0 + d];
#pragma unroll
        for (int r = 0; r < 4; r++) {
          int m = m0 + wm * 64 + mi * 16 + quad * 4 + r;
          int b = m >> 11, t = m & (T_ - 1);
          P[((size_t)((b * H_ + h) * T_ + t)) * HD_ + d] = f2bf(acc[mi][ni][r] + bv);
        }
      }
  }
}

// ---------------------------------------------------------------------------
// Round-2 fallback GEMM (f32 sources converted during staging) — used only if
// ws_size can't hold the bf16 pre-converted copies.
// ---------------------------------------------------------------------------
template<int A32, int B32, int MODE>
__global__ __launch_bounds__(256, 2)
void gemm_nt(const void* __restrict__ Ap, const void* __restrict__ Bp,
             const float* __restrict__ bias,
             float* __restrict__ Cout,
             unsigned short* __restrict__ Qb,
             unsigned short* __restrict__ Kb,
             unsigned short* __restrict__ Vb,
             int N, int K)
{
  __shared__ unsigned short Al[128 * 72];
  __shared__ unsigned short Bl[128 * 72];
  const int tid  = threadIdx.x;
  const int wave = tid >> 6, lane = tid & 63;
  const int quad = lane >> 4, l15 = lane & 15;
  const int wm = wave >> 1, wn = wave & 1;
  const int n0 = blockIdx.x * 128, m0 = blockIdx.y * 128;

  f32x4 acc[4][4];
#pragma unroll
  for (int i = 0; i < 4; i++)
#pragma unroll
    for (int j = 0; j < 4; j++) acc[i][j] = (f32x4){0.f, 0.f, 0.f, 0.f};

  for (int k0 = 0; k0 < K; k0 += 64) {
    __syncthreads();
    if constexpr (A32) {
      const float* A = (const float*)Ap;
#pragma unroll
      for (int i = 0; i < 8; i++) {
        int cid = tid + i * 256;
        int r = cid >> 4, c = cid & 15;
        float4 v = *(const float4*)&A[(size_t)(m0 + r) * K + k0 + c * 4];
        ushort4 h;
        h.x = f2bf(v.x); h.y = f2bf(v.y); h.z = f2bf(v.z); h.w = f2bf(v.w);
        *(ushort4*)&Al[r * 72 + c * 4] = h;
      }
    } else {
      const unsigned short* A = (const unsigned short*)Ap;
#pragma unroll
      for (int i = 0; i < 4; i++) {
        int cid = tid + i * 256;
        int r = cid >> 3, c = cid & 7;
        *(float4*)&Al[r * 72 + c * 8] =
            *(const float4*)&A[(size_t)(m0 + r) * K + k0 + c * 8];
      }
    }
    if constexpr (B32) {
      const float* Bm = (const float*)Bp;
#pragma unroll
      for (int i = 0; i < 8; i++) {
        int cid = tid + i * 256;
        int r = cid >> 4, c = cid & 15;
        float4 v = *(const float4*)&Bm[(size_t)(n0 + r) * K + k0 + c * 4];
        ushort4 h;
        h.x = f2bf(v.x); h.y = f2bf(v.y); h.z = f2bf(v.z); h.w = f2bf(v.w);
        *(ushort4*)&Bl[r * 72 + c * 4] = h;
      }
    } else {
      const unsigned short* Bm = (const unsigned short*)Bp;
#pragma unroll
      for (int i = 0; i < 4; i++) {
        int cid = tid + i * 256;
        int r = cid >> 3, c = cid & 7;
        *(float4*)&Bl[r * 72 + c * 8] =
            *(const float4*)&Bm[(size_t)(n0 + r) * K + k0 + c * 8];
      }
    }
    __syncthreads();
#pragma unroll
    for (int kc = 0; kc < 2; kc++) {
      short8 af[4], bfr[4];
#pragma unroll
      for (int mi = 0; mi < 4; mi++)
        af[mi] = *(const short8*)&Al[(wm * 64 + mi * 16 + l15) * 72 + kc * 32 + quad * 8];
#pragma unroll
      for (int ni = 0; ni < 4; ni++)
        bfr[ni] = *(const short8*)&Bl[(wn * 64 + ni * 16 + l15) * 72 + kc * 32 + quad * 8];
#pragma unroll
      for (int mi = 0; mi < 4; mi++)
#pragma unroll
        for (int ni = 0; ni < 4; ni++)
          acc[mi][ni] = __builtin_amdgcn_mfma_f32_16x16x32_bf16(af[mi], bfr[ni], acc[mi][ni], 0, 0, 0);
    }
  }

  if constexpr (MODE == 0) {
#pragma unroll
    for (int mi = 0; mi < 4; mi++)
#pragma unroll
      for (int ni = 0; ni < 4; ni++) {
        int col = n0 + wn * 64 + ni * 16 + l15;
        float bv = bias[col];
#pragma unroll
        for (int r = 0; r < 4; r++) {
          int row = m0 + wm * 64 + mi * 16 + quad * 4 + r;
          Cout[(size_t)row * N + col] = acc[mi][ni][r] + bv;
        }
      }
  } else {
    int which = n0 >> 11;
    int h = (n0 >> 7) & 15;
    unsigned short* P = (which == 0) ? Qb : (which == 1) ? Kb : Vb;
#pragma unroll
    for (int mi = 0; mi < 4; mi++)
#pragma unroll
      for (int ni = 0; ni < 4; ni++) {
        int d = wn * 64 + ni * 16 + l15;
        float bv = bias[n0 + d];
#pragma unroll
        for (int r = 0; r < 4; r++) {
          int m = m0 + wm * 64 + mi * 16 + quad * 4 + r;
          int b = m >> 11, t = m & (T_ - 1);
          P[((size_t)((b * H_ + h) * T_ + t)) * HD_ + d] = f2bf(acc[mi][ni][r] + bv);
        }
      }
  }
}

// ---------------------------------------------------------------------------
// RoPE in-place on bf16 Q and K, layout [B*H*T][128]. (unchanged, verified)
// theta_p = 10000^(-(2**p)/128), pos 1-indexed, pair (d, d+64).
// ---------------------------------------------------------------------------
__global__ void rope_k(unsigned short* __restrict__ Q, unsigned short* __restrict__ K)
{
  const int tid = threadIdx.x;
  const int w = tid >> 6, l = tid & 63;
  const int r = blockIdx.x * 4 + w;
  const int t = r & (T_ - 1);
  const float pos = (float)(t + 1);
  const float theta = expf(-exp2f((float)l) * 0.07195578415606394f); // ln(1e4)/128
  const float ang = pos * theta;
  const float c = cosf(ang), s = sinf(ang);
  const size_t base = (size_t)r * HD_;

  float q0 = bf2f(Q[base + l]), q1 = bf2f(Q[base + l + 64]);
  Q[base + l]      = f2bf(q0 * c - q1 * s);
  Q[base + l + 64] = f2bf(q1 * c + q0 * s);
  float k0 = bf2f(K[base + l]), k1 = bf2f(K[base + l + 64]);
  K[base + l]      = f2bf(k0 * c - k1 * s);
  K[base + l + 64] = f2bf(k1 * c + k0 * s);
}

// ---------------------------------------------------------------------------
// Flash-style causal attention (unchanged from round-2 passing version).
// ---------------------------------------------------------------------------
__global__ __launch_bounds__(256, 2)
void attn_k(const unsigned short* __restrict__ Q,
            const unsigned short* __restrict__ K,
            const unsigned short* __restrict__ V,
            unsigned short* __restrict__ AO)
{
  __shared__ unsigned short Kl[64 * 136];
  __shared__ unsigned short Vt[128 * 72];
  __shared__ unsigned short Pl[4 * 32 * 72];

  const int tid  = threadIdx.x;
  const int wave = tid >> 6, lane = tid & 63;
  const int quad = lane >> 4, l15 = lane & 15;
  const int blk = blockIdx.x;
  const int qb = blk & 15, bh = blk >> 4;
  const int q0 = qb * 128;
  const unsigned short* Qh = Q + (size_t)bh * T_ * HD_;
  const unsigned short* Kh = K + (size_t)bh * T_ * HD_;
  const unsigned short* Vh = V + (size_t)bh * T_ * HD_;

  short8 qf[2][4];
#pragma unroll
  for (int mi = 0; mi < 2; mi++)
#pragma unroll
    for (int kc = 0; kc < 4; kc++)
      qf[mi][kc] = *(const short8*)&Qh[(size_t)(q0 + wave * 32 + mi * 16 + l15) * HD_ + kc * 32 + quad * 8];

  f32x4 oacc[2][8];
#pragma unroll
  for (int mi = 0; mi < 2; mi++)
#pragma unroll
    for (int n = 0; n < 8; n++) oacc[mi][n] = (f32x4){0.f, 0.f, 0.f, 0.f};
  float mst[2][4], lst[2][4];
#pragma unroll
  for (int mi = 0; mi < 2; mi++)
#pragma unroll
    for (int r = 0; r < 4; r++) { mst[mi][r] = -1e30f; lst[mi][r] = 0.f; }

  const float scale = 0.08838834764831845f;  // 1/sqrt(128)
  const int ktend = q0 + 128;

  for (int kt = 0; kt < ktend; kt += 64) {
    __syncthreads();
#pragma unroll
    for (int i = 0; i < 4; i++) {
      int cid = tid + i * 256;
      int r = cid >> 4, c = cid & 15;
      *(float4*)&Kl[r * 136 + c * 8] =
          *(const float4*)&Kh[(size_t)(kt + r) * HD_ + c * 8];
    }
#pragma unroll
    for (int i = 0; i < 4; i++) {
      int cid = tid + i * 256;
      int r = cid >> 4, c = cid & 15;
      const unsigned short* src = &Vh[(size_t)(kt + r) * HD_ + c * 8];
#pragma unroll
      for (int j = 0; j < 8; j++) Vt[(c * 8 + j) * 72 + r] = src[j];
    }
    __syncthreads();

    f32x4 sa[2][4];
#pragma unroll
    for (int mi = 0; mi < 2; mi++)
#pragma unroll
      for (int ni = 0; ni < 4; ni++) sa[mi][ni] = (f32x4){0.f, 0.f, 0.f, 0.f};
#pragma unroll
    for (int kc = 0; kc < 4; kc++) {
      short8 bfr[4];
#pragma unroll
      for (int ni = 0; ni < 4; ni++)
        bfr[ni] = *(const short8*)&Kl[(ni * 16 + l15) * 136 + kc * 32 + quad * 8];
#pragma unroll
      for (int mi = 0; mi < 2; mi++)
#pragma unroll
        for (int ni = 0; ni < 4; ni++)
          sa[mi][ni] = __builtin_amdgcn_mfma_f32_16x16x32_bf16(qf[mi][kc], bfr[ni], sa[mi][ni], 0, 0, 0);
    }

#pragma unroll
    for (int mi = 0; mi < 2; mi++) {
      float rmax[4];
#pragma unroll
      for (int r = 0; r < 4; r++) rmax[r] = -1e30f;
#pragma unroll
      for (int ni = 0; ni < 4; ni++) {
        int gcol = kt + ni * 16 + l15;
#pragma unroll
        for (int r = 0; r < 4; r++) {
          int grow = q0 + wave * 32 + mi * 16 + quad * 4 + r;
          float v = sa[mi][ni][r] * scale;
          v = (gcol > grow) ? -1e30f : v;
          sa[mi][ni][r] = v;
          rmax[r] = fmaxf(rmax[r], v);
        }
      }
#pragma unroll
      for (int r = 0; r < 4; r++)
#pragma unroll
        for (int off = 1; off < 16; off <<= 1)
          rmax[r] = fmaxf(rmax[r], __shfl_xor(rmax[r], off));
      float alpha[4];
#pragma unroll
      for (int r = 0; r < 4; r++) {
        float mnew = fmaxf(mst[mi][r], rmax[r]);
        alpha[r] = __expf(fminf(mst[mi][r] - mnew, 0.f));
        mst[mi][r] = mnew;
      }
      float rsum[4] = {0.f, 0.f, 0.f, 0.f};
#pragma unroll
      for (int ni = 0; ni < 4; ni++)
#pragma unroll
        for (int r = 0; r < 4; r++) {
          float p = __expf(fminf(sa[mi][ni][r] - mst[mi][r], 0.f));
          sa[mi][ni][r] = p;
          rsum[r] += p;
        }
#pragma unroll
      for (int r = 0; r < 4; r++) {
#pragma unroll
        for (int off = 1; off < 16; off <<= 1)
          rsum[r] += __shfl_xor(rsum[r], off);
        lst[mi][r] = lst[mi][r] * alpha[r] + rsum[r];
      }
#pragma unroll
      for (int nv = 0; nv < 8; nv++)
#pragma unroll
        for (int r = 0; r < 4; r++) oacc[mi][nv][r] *= alpha[r];
#pragma unroll
      for (int ni = 0; ni < 4; ni++)
#pragma unroll
        for (int r = 0; r < 4; r++)
          Pl[wave * 32 * 72 + (mi * 16 + quad * 4 + r) * 72 + ni * 16 + l15] = f2bf(sa[mi][ni][r]);
    }
    __syncthreads();

    short8 pf[2][2];
#pragma unroll
    for (int mi = 0; mi < 2; mi++)
#pragma unroll
      for (int kc = 0; kc < 2; kc++)
        pf[mi][kc] = *(const short8*)&Pl[wave * 32 * 72 + (mi * 16 + l15) * 72 + kc * 32 + quad * 8];
#pragma unroll
    for (int nv = 0; nv < 8; nv++)
#pragma unroll
      for (int kc = 0; kc < 2; kc++) {
        short8 vb = *(const short8*)&Vt[(nv * 16 + l15) * 72 + kc * 32 + quad * 8];
#pragma unroll
        for (int mi = 0; mi < 2; mi++)
          oacc[mi][nv] = __builtin_amdgcn_mfma_f32_16x16x32_bf16(pf[mi][kc], vb, oacc[mi][nv], 0, 0, 0);
      }
  }

  const int b = bh >> 4, h = bh & 15;
#pragma unroll
  for (int mi = 0; mi < 2; mi++) {
    float linv[4];
#pragma unroll
    for (int r = 0; r < 4; r++) linv[r] = 1.0f / fmaxf(lst[mi][r], 1e-20f);
#pragma unroll
    for (int nv = 0; nv < 8; nv++)
#pragma unroll
      for (int r = 0; r < 4; r++) {
        int t = q0 + wave * 32 + mi * 16 + quad * 4 + r;
        int d = nv * 16 + l15;
        AO[((size_t)(b * T_ + t)) * C_ + h * HD_ + d] = f2bf(oacc[mi][nv][r] * linv[r]);
      }
  }
}

// ---------------------------------------------------------------------------
extern "C" void kernel_launch(void* const* d_in, const int* in_sizes, int n_in,
                              void* d_out, int out_size, void* d_ws, size_t ws_size,
                              hipStream_t stream)
{
  const float* x    = (const float*)d_in[0];  // [2,2048,2048] f32
  const float* Wqkv = (const float*)d_in[1];  // [6144,2048]   f32
  const float* bqkv = (const float*)d_in[2];  // [6144]        f32
  const float* Wo   = (const float*)d_in[3];  // [2048,2048]   f32
  const float* bo   = (const float*)d_in[4];  // [2048]        f32
  float* out = (float*)d_out;                 // [2,2048,2048] f32

  const size_t SZ   = (size_t)B_ * H_ * T_ * HD_;   // 8,388,608
  const size_t NX   = SZ;                            // x elems
  const size_t NWQ  = (size_t)3 * C_ * C_;           // 12,582,912
  const size_t NWO  = (size_t)C_ * C_;               // 4,194,304
  unsigned short* ws = (unsigned short*)d_ws;

  dim3 blk(256, 1, 1);
  const size_t need = (NX + NWQ + 3 * SZ) * sizeof(unsigned short);  // 92.3 MB

  if (ws_size >= need) {
    // fast path: bf16 pre-converted operands + async-staged m97 GEMMs
    unsigned short* xb    = ws;
    unsigned short* Wqkvb = xb + NX;
    unsigned short* Qb    = Wqkvb + NWQ;
    unsigned short* Kb    = Qb + SZ;
    unsigned short* Vb    = Kb + SZ;
    unsigned short* AO    = xb;      // alias: x dead after QKV GEMM
    unsigned short* Wob   = Wqkvb;   // alias: Wqkv dead after QKV GEMM

    cvt_k<<<dim3((unsigned)(NX / 1024)), blk, 0, stream>>>(x, xb, (int)(NX / 4));
    cvt_k<<<dim3((unsigned)(NWQ / 1024)), blk, 0, stream>>>(Wqkv, Wqkvb, (int)(NWQ / 4));
    gemm_bt<1><<<dim3(48, 32, 1), blk, 0, stream>>>(
        xb, Wqkvb, bqkv, nullptr, Qb, Kb, Vb, 6144, 2048);
    cvt_k<<<dim3((unsigned)(NWO / 1024)), blk, 0, stream>>>(Wo, Wob, (int)(NWO / 4));
    rope_k<<<dim3((B_ * H_ * T_) / 4, 1, 1), blk, 0, stream>>>(Qb, Kb);
    attn_k<<<dim3(512, 1, 1), blk, 0, stream>>>(Qb, Kb, Vb, AO);
    gemm_bt<0><<<dim3(16, 32, 1), blk, 0, stream>>>(
        AO, Wob, bo, out, nullptr, nullptr, nullptr, 2048, 2048);
  } else {
    // fallback: round-2 path (64 MB ws)
    unsigned short* Qb = ws;
    unsigned short* Kb = Qb + SZ;
    unsigned short* Vb = Kb + SZ;
    unsigned short* AO = Vb + SZ;
    gemm_nt<1, 1, 1><<<dim3(48, 32, 1), blk, 0, stream>>>(
        (const void*)x, (const void*)Wqkv, bqkv, nullptr, Qb, Kb, Vb, 6144, 2048);
    rope_k<<<dim3((B_ * H_ * T_) / 4, 1, 1), blk, 0, stream>>>(Qb, Kb);
    attn_k<<<dim3(512, 1, 1), blk, 0, stream>>>(Qb, Kb, Vb, AO);
    gemm_nt<0, 1, 0><<<dim3(16, 32, 1), blk, 0, stream>>>(
        (const void*)AO, (const void*)Wo, bo, out, nullptr, nullptr, nullptr, 2048, 2048);
  }
}

// Round 4
// 479.746 us; speedup vs baseline: 2.0196x; 1.1896x over previous
//
#include <hip/hip_runtime.h>
#include <hip/hip_bf16.h>

// Problem: B=2, T=2048, C=2048, H=16, HD=128.
// Inputs/outputs FLOAT32 (per reference); internal compute bf16 MFMA.
// Round 4: attention rewrite — V pre-transposed at QKV epilogue (kills the
// 16-way LDS bank conflicts of per-tile transposes), complementary-pair
// Q-tile scheduling (uniform 33 k-iters/block), global_load_lds staging for
// K and V, exp2-based softmax with scale folded into Q at rope time.

typedef __attribute__((ext_vector_type(8))) short short8;   // 8 bf16 MFMA A/B frag
typedef __attribute__((ext_vector_type(4))) float f32x4;    // MFMA C/D frag

#define B_  2
#define T_  2048
#define C_  2048
#define H_  16
#define HD_ 128

__device__ __forceinline__ float bf2f(unsigned short u) {
  union { unsigned int i; float f; } v; v.i = ((unsigned int)u) << 16; return v.f;
}
__device__ __forceinline__ unsigned short f2bf(float f) {
  union { float f; unsigned int i; } v; v.f = f;
  unsigned int x = v.i;
  return (unsigned short)((x + 0x7fffu + ((x >> 16) & 1u)) >> 16);  // RNE
}
__device__ __forceinline__ float fexp2(float x) {
#if __has_builtin(__builtin_amdgcn_exp2f)
  return __builtin_amdgcn_exp2f(x);
#else
  return exp2f(x);
#endif
}

// async 16B global->LDS; lds base wave-uniform, lane l lands at base + l*16.
__device__ __forceinline__ void gll16(const unsigned short* g, unsigned short* lds_base) {
  __builtin_amdgcn_global_load_lds(
      (const __attribute__((address_space(1))) void*)g,
      (__attribute__((address_space(3))) void*)lds_base, 16, 0, 0);
}

// ---------------------------------------------------------------------------
// f32 -> bf16 elementwise convert, 4 elems/thread.
// ---------------------------------------------------------------------------
__global__ void cvt_k(const float* __restrict__ src, unsigned short* __restrict__ dst, int n4)
{
  int i = blockIdx.x * blockDim.x + threadIdx.x;
  if (i < n4) {
    float4 v = ((const float4*)src)[i];
    ushort4 h;
    h.x = f2bf(v.x); h.y = f2bf(v.y); h.z = f2bf(v.z); h.w = f2bf(v.w);
    ((ushort4*)dst)[i] = h;
  }
}

// ---------------------------------------------------------------------------
// m97-style NT GEMM (bf16 x bf16): C[M][N] = A[M][K]*Bw[N][K]^T + bias.
// 128x128 tile, BK=64, 2x2 waves of 64x64, 4x4 16x16x32 MFMA frags,
// global_load_lds width=16 staging (874 TF structure, learn_hip m97).
// MODE 0: f32 row-major store. MODE 1: bf16 qkv scatter:
//   Q,K -> [bh][t][d];  V -> TRANSPOSED [bh][d][t] (for attn B-frag staging).
// MFMA layouts (HW-verified m89/m91): A: A[m=lane&15][k=quad*8+j];
// B: B[k=quad*8+j][n=lane&15]; C/D: col=lane&15, row=quad*4+reg.
// ---------------------------------------------------------------------------
template<int MODE>
__global__ __launch_bounds__(256, 2)
void gemm_bt(const unsigned short* __restrict__ A,
             const unsigned short* __restrict__ Bw,
             const float* __restrict__ bias,
             float* __restrict__ Cout,
             unsigned short* __restrict__ Qb,
             unsigned short* __restrict__ Kb,
             unsigned short* __restrict__ Vb,
             int N, int K)
{
  __shared__ unsigned short Al[128 * 64];
  __shared__ unsigned short Bl[128 * 64];
  const int tid  = threadIdx.x;
  const int wave = tid >> 6, lane = tid & 63;
  const int quad = lane >> 4, l15 = lane & 15;
  const int wm = wave >> 1, wn = wave & 1;
  const int n0 = blockIdx.x * 128, m0 = blockIdx.y * 128;

  f32x4 acc[4][4];
#pragma unroll
  for (int i = 0; i < 4; i++)
#pragma unroll
    for (int j = 0; j < 4; j++) acc[i][j] = (f32x4){0.f, 0.f, 0.f, 0.f};

  for (int k0 = 0; k0 < K; k0 += 64) {
    __syncthreads();
    const unsigned short* Ag = A + (size_t)m0 * K + k0;
    const unsigned short* Bg = Bw + (size_t)n0 * K + k0;
#pragma unroll
    for (int i = 0; i < 4; i++) {
      int cc = i * 256 + wave * 64 + lane;      // 16B chunk id, 0..1023
      int r = cc >> 3, c8 = cc & 7;
      gll16(Ag + (size_t)r * K + c8 * 8, &Al[(i * 4 + wave) * 512]);
      gll16(Bg + (size_t)r * K + c8 * 8, &Bl[(i * 4 + wave) * 512]);
    }
    __syncthreads();
#pragma unroll
    for (int kc = 0; kc < 2; kc++) {
      short8 af[4], bfr[4];
#pragma unroll
      for (int mi = 0; mi < 4; mi++)
        af[mi] = *(const short8*)&Al[(wm * 64 + mi * 16 + l15) * 64 + kc * 32 + quad * 8];
#pragma unroll
      for (int ni = 0; ni < 4; ni++)
        bfr[ni] = *(const short8*)&Bl[(wn * 64 + ni * 16 + l15) * 64 + kc * 32 + quad * 8];
#pragma unroll
      for (int mi = 0; mi < 4; mi++)
#pragma unroll
        for (int ni = 0; ni < 4; ni++)
          acc[mi][ni] = __builtin_amdgcn_mfma_f32_16x16x32_bf16(af[mi], bfr[ni], acc[mi][ni], 0, 0, 0);
    }
  }

  if constexpr (MODE == 0) {
#pragma unroll
    for (int mi = 0; mi < 4; mi++)
#pragma unroll
      for (int ni = 0; ni < 4; ni++) {
        int col = n0 + wn * 64 + ni * 16 + l15;
        float bv = bias[col];
#pragma unroll
        for (int r = 0; r < 4; r++) {
          int row = m0 + wm * 64 + mi * 16 + quad * 4 + r;
          Cout[(size_t)row * N + col] = acc[mi][ni][r] + bv;
        }
      }
  } else {
    int which = n0 >> 11;
    int h = (n0 >> 7) & 15;
    unsigned short* P = (which == 0) ? Qb : (which == 1) ? Kb : Vb;
#pragma unroll
    for (int mi = 0; mi < 4; mi++)
#pragma unroll
      for (int ni = 0; ni < 4; ni++) {
        int d = wn * 64 + ni * 16 + l15;
        float bv = bias[n0 + d];
#pragma unroll
        for (int r = 0; r < 4; r++) {
          int m = m0 + wm * 64 + mi * 16 + quad * 4 + r;
          int b = m >> 11, t = m & (T_ - 1);
          size_t addr = (which == 2)
              ? ((size_t)((b * H_ + h) * HD_ + d)) * T_ + t    // V transposed
              : ((size_t)((b * H_ + h) * T_ + t)) * HD_ + d;   // Q,K row-major
          P[addr] = f2bf(acc[mi][ni][r] + bv);
        }
      }
  }
}

// ---------------------------------------------------------------------------
// RoPE in-place on bf16 Q and K, layout [B*H*T][128].
// theta_p = 10000^(-(2**p)/128) (faithful 2**p quirk), pos 1-indexed,
// pair (d, d+64). Q additionally pre-scaled by 1/sqrt(HD) * log2(e) so the
// attention softmax can use exp2 with no per-element scale multiply.
// ---------------------------------------------------------------------------
__global__ void rope_k(unsigned short* __restrict__ Q, unsigned short* __restrict__ K)
{
  const int tid = threadIdx.x;
  const int w = tid >> 6, l = tid & 63;
  const int r = blockIdx.x * 4 + w;
  const int t = r & (T_ - 1);
  const float pos = (float)(t + 1);
  const float theta = expf(-exp2f((float)l) * 0.07195578415606394f); // ln(1e4)/128
  const float ang = pos * theta;
  const float c = cosf(ang), s = sinf(ang);
  const float QS = 0.08838834764831845f * 1.4426950408889634f; // 1/sqrt(128)*log2(e)
  const size_t base = (size_t)r * HD_;

  float q0 = bf2f(Q[base + l]), q1 = bf2f(Q[base + l + 64]);
  Q[base + l]      = f2bf((q0 * c - q1 * s) * QS);
  Q[base + l + 64] = f2bf((q1 * c + q0 * s) * QS);
  float k0 = bf2f(K[base + l]), k1 = bf2f(K[base + l + 64]);
  K[base + l]      = f2bf(k0 * c - k1 * s);
  K[base + l + 64] = f2bf(k1 * c + k0 * s);
}

// ---------------------------------------------------------------------------
// Flash-style causal attention, round-4 structure.
// Grid 512 = (bh 32) x (qpair 16), XCD-swizzled so each bh's blocks share an
// XCD L2 (K+V per bh = 1 MB; 4 bh per XCD = 4 MB = L2). Each block processes
// TWO 64-row Q-tiles (qp*64 and (31-qp)*64) -> uniform 33 k-iters per block.
// 4 waves x 16 rows. K and V staged via global_load_lds width=16 (V already
// transposed in global: [bh][d][t] -> coalesced rows, no LDS transpose).
// Q pre-scaled by 1/sqrt(HD)*log2e -> softmax uses native exp2.
// P round-trips LDS (C/D -> A layout, m120 pattern), stride 72 (2-way, free).
// Output [B][T][H*HD] bf16 for the final GEMM.
// ---------------------------------------------------------------------------
__global__ __launch_bounds__(256, 2)
void attn_k(const unsigned short* __restrict__ Q,
            const unsigned short* __restrict__ K,
            const unsigned short* __restrict__ Vt_g,
            unsigned short* __restrict__ AO)
{
  __shared__ unsigned short Kl[64 * 128];   // K rows [kv][d], gll landing order
  __shared__ unsigned short Vl[128 * 64];   // V^T rows [d][kv], gll landing order
  __shared__ unsigned short Pl[4 * 16 * 72];// per-wave P stripe [16][72]

  const int tid  = threadIdx.x;
  const int wave = tid >> 6, lane = tid & 63;
  const int quad = lane >> 4, l15 = lane & 15;
  // swizzle: xcd slot = blk&7; bh = slot + 8*((blk>>3)&3); qp = blk>>5
  const int blk = blockIdx.x;
  const int bh = (blk & 7) + 8 * ((blk >> 3) & 3);
  const int qp = (blk >> 5) & 15;
  const unsigned short* Qh = Q    + (size_t)bh * T_ * HD_;
  const unsigned short* Kh = K    + (size_t)bh * T_ * HD_;
  const unsigned short* Vh = Vt_g + (size_t)bh * T_ * HD_;  // [d][t]
  const int b = bh >> 4, h = bh & 15;

#pragma unroll
  for (int tile = 0; tile < 2; tile++) {
    const int q0 = (tile == 0 ? qp : 31 - qp) * 64;
    const int wq = q0 + wave * 16;            // this wave's 16 q-rows
    // Q A-frags (already scaled by 1/sqrt(HD)*log2e at rope time)
    short8 qf[4];
#pragma unroll
    for (int kc = 0; kc < 4; kc++)
      qf[kc] = *(const short8*)&Qh[(size_t)(wq + l15) * HD_ + kc * 32 + quad * 8];

    f32x4 oacc[8];
#pragma unroll
    for (int n = 0; n < 8; n++) oacc[n] = (f32x4){0.f, 0.f, 0.f, 0.f};
    float mst[4], lst[4];
#pragma unroll
    for (int r = 0; r < 4; r++) { mst[r] = -1e30f; lst[r] = 0.f; }

    const int niter = (q0 >> 6) + 1;
    for (int it = 0; it < niter; it++) {
      const int kt = it * 64;
      __syncthreads();                        // prior Kl/Vl/Pl reads done
      // stage K tile [64][128] and V^T tile [128][64], 4 gll16 each/thread
#pragma unroll
      for (int i = 0; i < 4; i++) {
        int cc = i * 256 + wave * 64 + lane;  // 0..1023
        gll16(Kh + (size_t)(kt + (cc >> 4)) * HD_ + (cc & 15) * 8,
              &Kl[(i * 4 + wave) * 512]);
        gll16(Vh + (size_t)(cc >> 3) * T_ + kt + (cc & 7) * 8,
              &Vl[(i * 4 + wave) * 512]);
      }
      __syncthreads();                        // vmcnt drained -> LDS valid

      // S' = (Q*s) K^T  (16 rows x 64 cols per wave)
      f32x4 sa[4];
#pragma unroll
      for (int ni = 0; ni < 4; ni++) sa[ni] = (f32x4){0.f, 0.f, 0.f, 0.f};
#pragma unroll
      for (int kc = 0; kc < 4; kc++) {
        short8 bfr[4];
#pragma unroll
        for (int ni = 0; ni < 4; ni++)
          bfr[ni] = *(const short8*)&Kl[(ni * 16 + l15) * HD_ + kc * 32 + quad * 8];
#pragma unroll
        for (int ni = 0; ni < 4; ni++)
          sa[ni] = __builtin_amdgcn_mfma_f32_16x16x32_bf16(qf[kc], bfr[ni], sa[ni], 0, 0, 0);
      }

      // causal mask only on the diagonal tile (uniform branch)
      if (kt == q0) {
#pragma unroll
        for (int ni = 0; ni < 4; ni++) {
          int gcol = kt + ni * 16 + l15;
#pragma unroll
          for (int r = 0; r < 4; r++) {
            int grow = wq + quad * 4 + r;
            if (gcol > grow) sa[ni][r] = -1e30f;
          }
        }
      }

      // online softmax (base-2; scale already folded into Q)
      float rmax[4] = {-1e30f, -1e30f, -1e30f, -1e30f};
#pragma unroll
      for (int ni = 0; ni < 4; ni++)
#pragma unroll
        for (int r = 0; r < 4; r++) rmax[r] = fmaxf(rmax[r], sa[ni][r]);
#pragma unroll
      for (int r = 0; r < 4; r++)
#pragma unroll
        for (int off = 1; off < 16; off <<= 1)
          rmax[r] = fmaxf(rmax[r], __shfl_xor(rmax[r], off));
      float alpha[4];
#pragma unroll
      for (int r = 0; r < 4; r++) {
        float mnew = fmaxf(mst[r], rmax[r]);
        alpha[r] = fexp2(fminf(mst[r] - mnew, 0.f));
        mst[r] = mnew;
      }
      float rsum[4] = {0.f, 0.f, 0.f, 0.f};
#pragma unroll
      for (int ni = 0; ni < 4; ni++)
#pragma unroll
        for (int r = 0; r < 4; r++) {
          float p = fexp2(fminf(sa[ni][r] - mst[r], 0.f));
          sa[ni][r] = p;
          rsum[r] += p;
        }
#pragma unroll
      for (int r = 0; r < 4; r++) {
#pragma unroll
        for (int off = 1; off < 16; off <<= 1)
          rsum[r] += __shfl_xor(rsum[r], off);
        lst[r] = lst[r] * alpha[r] + rsum[r];
      }
#pragma unroll
      for (int nv = 0; nv < 8; nv++)
#pragma unroll
        for (int r = 0; r < 4; r++) oacc[nv][r] *= alpha[r];
      // P (C/D layout) -> LDS (A layout source), per-wave stripe
#pragma unroll
      for (int ni = 0; ni < 4; ni++)
#pragma unroll
        for (int r = 0; r < 4; r++)
          Pl[wave * 16 * 72 + (quad * 4 + r) * 72 + ni * 16 + l15] = f2bf(sa[ni][r]);
      __syncthreads();                        // P visible (and Vl reads ordered)

      // O += P V : A-frags from Pl, B-frags from Vl (V^T rows)
      short8 pf[2];
#pragma unroll
      for (int kc = 0; kc < 2; kc++)
        pf[kc] = *(const short8*)&Pl[wave * 16 * 72 + l15 * 72 + kc * 32 + quad * 8];
#pragma unroll
      for (int nv = 0; nv < 8; nv++)
#pragma unroll
        for (int kc = 0; kc < 2; kc++) {
          short8 vb = *(const short8*)&Vl[(nv * 16 + l15) * 64 + kc * 32 + quad * 8];
          oacc[nv] = __builtin_amdgcn_mfma_f32_16x16x32_bf16(pf[kc], vb, oacc[nv], 0, 0, 0);
        }
    }

    // epilogue: normalize, store as [B][T][H*HD]
    float linv[4];
#pragma unroll
    for (int r = 0; r < 4; r++) linv[r] = 1.0f / fmaxf(lst[r], 1e-20f);
#pragma unroll
    for (int nv = 0; nv < 8; nv++)
#pragma unroll
      for (int r = 0; r < 4; r++) {
        int t = wq + quad * 4 + r;
        int d = nv * 16 + l15;
        AO[((size_t)(b * T_ + t)) * C_ + h * HD_ + d] = f2bf(oacc[nv][r] * linv[r]);
      }
  }
}

// ---------------------------------------------------------------------------
// Fallback GEMM (f32 sources converted during staging) — used only if ws is
// too small for the bf16 pre-converted copies. V store transposed to match.
// ---------------------------------------------------------------------------
template<int A32, int B32, int MODE>
__global__ __launch_bounds__(256, 2)
void gemm_nt(const void* __restrict__ Ap, const void* __restrict__ Bp,
             const float* __restrict__ bias,
             float* __restrict__ Cout,
             unsigned short* __restrict__ Qb,
             unsigned short* __restrict__ Kb,
             unsigned short* __restrict__ Vb,
             int N, int K)
{
  __shared__ unsigned short Al[128 * 72];
  __shared__ unsigned short Bl[128 * 72];
  const int tid  = threadIdx.x;
  const int wave = tid >> 6, lane = tid & 63;
  const int quad = lane >> 4, l15 = lane & 15;
  const int wm = wave >> 1, wn = wave & 1;
  const int n0 = blockIdx.x * 128, m0 = blockIdx.y * 128;

  f32x4 acc[4][4];
#pragma unroll
  for (int i = 0; i < 4; i++)
#pragma unroll
    for (int j = 0; j < 4; j++) acc[i][j] = (f32x4){0.f, 0.f, 0.f, 0.f};

  for (int k0 = 0; k0 < K; k0 += 64) {
    __syncthreads();
    if constexpr (A32) {
      const float* A = (const float*)Ap;
#pragma unroll
      for (int i = 0; i < 8; i++) {
        int cid = tid + i * 256;
        int r = cid >> 4, c = cid & 15;
        float4 v = *(const float4*)&A[(size_t)(m0 + r) * K + k0 + c * 4];
        ushort4 hh;
        hh.x = f2bf(v.x); hh.y = f2bf(v.y); hh.z = f2bf(v.z); hh.w = f2bf(v.w);
        *(ushort4*)&Al[r * 72 + c * 4] = hh;
      }
    } else {
      const unsigned short* A = (const unsigned short*)Ap;
#pragma unroll
      for (int i = 0; i < 4; i++) {
        int cid = tid + i * 256;
        int r = cid >> 3, c = cid & 7;
        *(float4*)&Al[r * 72 + c * 8] =
            *(const float4*)&A[(size_t)(m0 + r) * K + k0 + c * 8];
      }
    }
    if constexpr (B32) {
      const float* Bm = (const float*)Bp;
#pragma unroll
      for (int i = 0; i < 8; i++) {
        int cid = tid + i * 256;
        int r = cid >> 4, c = cid & 15;
        float4 v = *(const float4*)&Bm[(size_t)(n0 + r) * K + k0 + c * 4];
        ushort4 hh;
        hh.x = f2bf(v.x); hh.y = f2bf(v.y); hh.z = f2bf(v.z); hh.w = f2bf(v.w);
        *(ushort4*)&Bl[r * 72 + c * 4] = hh;
      }
    } else {
      const unsigned short* Bm = (const unsigned short*)Bp;
#pragma unroll
      for (int i = 0; i < 4; i++) {
        int cid = tid + i * 256;
        int r = cid >> 3, c = cid & 7;
        *(float4*)&Bl[r * 72 + c * 8] =
            *(const float4*)&Bm[(size_t)(n0 + r) * K + k0 + c * 8];
      }
    }
    __syncthreads();
#pragma unroll
    for (int kc = 0; kc < 2; kc++) {
      short8 af[4], bfr[4];
#pragma unroll
      for (int mi = 0; mi < 4; mi++)
        af[mi] = *(const short8*)&Al[(wm * 64 + mi * 16 + l15) * 72 + kc * 32 + quad * 8];
#pragma unroll
      for (int ni = 0; ni < 4; ni++)
        bfr[ni] = *(const short8*)&Bl[(wn * 64 + ni * 16 + l15) * 72 + kc * 32 + quad * 8];
#pragma unroll
      for (int mi = 0; mi < 4; mi++)
#pragma unroll
        for (int ni = 0; ni < 4; ni++)
          acc[mi][ni] = __builtin_amdgcn_mfma_f32_16x16x32_bf16(af[mi], bfr[ni], acc[mi][ni], 0, 0, 0);
    }
  }

  if constexpr (MODE == 0) {
#pragma unroll
    for (int mi = 0; mi < 4; mi++)
#pragma unroll
      for (int ni = 0; ni < 4; ni++) {
        int col = n0 + wn * 64 + ni * 16 + l15;
        float bv = bias[col];
#pragma unroll
        for (int r = 0; r < 4; r++) {
          int row = m0 + wm * 64 + mi * 16 + quad * 4 + r;
          Cout[(size_t)row * N + col] = acc[mi][ni][r] + bv;
        }
      }
  } else {
    int which = n0 >> 11;
    int h = (n0 >> 7) & 15;
    unsigned short* P = (which == 0) ? Qb : (which == 1) ? Kb : Vb;
#pragma unroll
    for (int mi = 0; mi < 4; mi++)
#pragma unroll
      for (int ni = 0; ni < 4; ni++) {
        int d = wn * 64 + ni * 16 + l15;
        float bv = bias[n0 + d];
#pragma unroll
        for (int r = 0; r < 4; r++) {
          int m = m0 + wm * 64 + mi * 16 + quad * 4 + r;
          int b = m >> 11, t = m & (T_ - 1);
          size_t addr = (which == 2)
              ? ((size_t)((b * H_ + h) * HD_ + d)) * T_ + t
              : ((size_t)((b * H_ + h) * T_ + t)) * HD_ + d;
          P[addr] = f2bf(acc[mi][ni][r] + bv);
        }
      }
  }
}

// ---------------------------------------------------------------------------
extern "C" void kernel_launch(void* const* d_in, const int* in_sizes, int n_in,
                              void* d_out, int out_size, void* d_ws, size_t ws_size,
                              hipStream_t stream)
{
  const float* x    = (const float*)d_in[0];  // [2,2048,2048] f32
  const float* Wqkv = (const float*)d_in[1];  // [6144,2048]   f32
  const float* bqkv = (const float*)d_in[2];  // [6144]        f32
  const float* Wo   = (const float*)d_in[3];  // [2048,2048]   f32
  const float* bo   = (const float*)d_in[4];  // [2048]        f32
  float* out = (float*)d_out;                 // [2,2048,2048] f32

  const size_t SZ   = (size_t)B_ * H_ * T_ * HD_;   // 8,388,608
  const size_t NX   = SZ;
  const size_t NWQ  = (size_t)3 * C_ * C_;
  const size_t NWO  = (size_t)C_ * C_;
  unsigned short* ws = (unsigned short*)d_ws;

  dim3 blk(256, 1, 1);
  const size_t need = (NX + NWQ + 3 * SZ) * sizeof(unsigned short);  // 92.3 MB

  if (ws_size >= need) {
    unsigned short* xb    = ws;
    unsigned short* Wqkvb = xb + NX;
    unsigned short* Qb    = Wqkvb + NWQ;
    unsigned short* Kb    = Qb + SZ;
    unsigned short* Vb    = Kb + SZ;      // transposed [bh][d][t]
    unsigned short* AO    = xb;           // alias: x dead after QKV GEMM
    unsigned short* Wob   = Wqkvb;        // alias: Wqkv dead after QKV GEMM

    cvt_k<<<dim3((unsigned)(NX / 1024)), blk, 0, stream>>>(x, xb, (int)(NX / 4));
    cvt_k<<<dim3((unsigned)(NWQ / 1024)), blk, 0, stream>>>(Wqkv, Wqkvb, (int)(NWQ / 4));
    gemm_bt<1><<<dim3(48, 32, 1), blk, 0, stream>>>(
        xb, Wqkvb, bqkv, nullptr, Qb, Kb, Vb, 6144, 2048);
    cvt_k<<<dim3((unsigned)(NWO / 1024)), blk, 0, stream>>>(Wo, Wob, (int)(NWO / 4));
    rope_k<<<dim3((B_ * H_ * T_) / 4, 1, 1), blk, 0, stream>>>(Qb, Kb);
    attn_k<<<dim3(512, 1, 1), blk, 0, stream>>>(Qb, Kb, Vb, AO);
    gemm_bt<0><<<dim3(16, 32, 1), blk, 0, stream>>>(
        AO, Wob, bo, out, nullptr, nullptr, nullptr, 2048, 2048);
  } else {
    unsigned short* Qb = ws;
    unsigned short* Kb = Qb + SZ;
    unsigned short* Vb = Kb + SZ;
    unsigned short* AO = Vb + SZ;
    gemm_nt<1, 1, 1><<<dim3(48, 32, 1), blk, 0, stream>>>(
        (const void*)x, (const void*)Wqkv, bqkv, nullptr, Qb, Kb, Vb, 6144, 2048);
    rope_k<<<dim3((B_ * H_ * T_) / 4, 1, 1), blk, 0, stream>>>(Qb, Kb);
    attn_k<<<dim3(512, 1, 1), blk, 0, stream>>>(Qb, Kb, Vb, AO);
    gemm_nt<0, 1, 0><<<dim3(16, 32, 1), blk, 0, stream>>>(
        (const void*)AO, (const void*)Wo, bo, out, nullptr, nullptr, nullptr, 2048, 2048);
  }
}

// Round 5
// 385.518 us; speedup vs baseline: 2.5132x; 1.2444x over previous
//
#include <hip/hip_runtime.h>
#include <hip/hip_bf16.h>

// Problem: B=2, T=2048, C=2048, H=16, HD=128.
// Inputs/outputs FLOAT32 (per reference); internal compute bf16 MFMA.
// Round 5: XOR-swizzled LDS layouts. The gll16 (global_load_lds) landing
// pattern forces unpadded tiles (row stride 32 dwords == 0 mod 32 -> 16-way
// ds_read_b128 conflicts, 3.8e7 counted in round 4). Fix: swizzle the SOURCE
// column per lane so LDS slot (r,c) holds global (r, c^(r&7)); fragment
// reads then XOR the col-chunk with row&7 -> lanes fan across all banks,
// residual 2-way aliasing only (free, m136). Same for attn K/V tiles.

typedef __attribute__((ext_vector_type(8))) short short8;   // 8 bf16 MFMA A/B frag
typedef __attribute__((ext_vector_type(4))) float f32x4;    // MFMA C/D frag

#define B_  2
#define T_  2048
#define C_  2048
#define H_  16
#define HD_ 128

__device__ __forceinline__ float bf2f(unsigned short u) {
  union { unsigned int i; float f; } v; v.i = ((unsigned int)u) << 16; return v.f;
}
__device__ __forceinline__ unsigned short f2bf(float f) {
  union { float f; unsigned int i; } v; v.f = f;
  unsigned int x = v.i;
  return (unsigned short)((x + 0x7fffu + ((x >> 16) & 1u)) >> 16);  // RNE
}
__device__ __forceinline__ float fexp2(float x) {
#if __has_builtin(__builtin_amdgcn_exp2f)
  return __builtin_amdgcn_exp2f(x);
#else
  return exp2f(x);
#endif
}

// async 16B global->LDS; lds base wave-uniform, lane l lands at base + l*16.
__device__ __forceinline__ void gll16(const unsigned short* g, unsigned short* lds_base) {
  __builtin_amdgcn_global_load_lds(
      (const __attribute__((address_space(1))) void*)g,
      (__attribute__((address_space(3))) void*)lds_base, 16, 0, 0);
}

// ---------------------------------------------------------------------------
// f32 -> bf16 elementwise convert, 4 elems/thread.
// ---------------------------------------------------------------------------
__global__ void cvt_k(const float* __restrict__ src, unsigned short* __restrict__ dst, int n4)
{
  int i = blockIdx.x * blockDim.x + threadIdx.x;
  if (i < n4) {
    float4 v = ((const float4*)src)[i];
    ushort4 h;
    h.x = f2bf(v.x); h.y = f2bf(v.y); h.z = f2bf(v.z); h.w = f2bf(v.w);
    ((ushort4*)dst)[i] = h;
  }
}

// ---------------------------------------------------------------------------
// m97-style NT GEMM (bf16 x bf16): C[M][N] = A[M][K]*Bw[N][K]^T + bias.
// 128x128 tile, BK=64, 2x2 waves of 64x64, 4x4 16x16x32 MFMA frags,
// global_load_lds width=16 staging, XOR-swizzled LDS columns (see header).
// MODE 0: f32 row-major store. MODE 1: bf16 qkv scatter:
//   Q,K -> [bh][t][d];  V -> TRANSPOSED [bh][d][t].
// MFMA layouts (HW-verified m89/m91): A: A[m=lane&15][k=quad*8+j];
// B: B[k=quad*8+j][n=lane&15]; C/D: col=lane&15, row=quad*4+reg.
// ---------------------------------------------------------------------------
template<int MODE>
__global__ __launch_bounds__(256, 2)
void gemm_bt(const unsigned short* __restrict__ A,
             const unsigned short* __restrict__ Bw,
             const float* __restrict__ bias,
             float* __restrict__ Cout,
             unsigned short* __restrict__ Qb,
             unsigned short* __restrict__ Kb,
             unsigned short* __restrict__ Vb,
             int N, int K)
{
  __shared__ unsigned short Al[128 * 64];
  __shared__ unsigned short Bl[128 * 64];
  const int tid  = threadIdx.x;
  const int wave = tid >> 6, lane = tid & 63;
  const int quad = lane >> 4, l15 = lane & 15;
  const int wm = wave >> 1, wn = wave & 1;
  const int n0 = blockIdx.x * 128, m0 = blockIdx.y * 128;

  f32x4 acc[4][4];
#pragma unroll
  for (int i = 0; i < 4; i++)
#pragma unroll
    for (int j = 0; j < 4; j++) acc[i][j] = (f32x4){0.f, 0.f, 0.f, 0.f};

  for (int k0 = 0; k0 < K; k0 += 64) {
    __syncthreads();
    const unsigned short* Ag = A + (size_t)m0 * K + k0;
    const unsigned short* Bg = Bw + (size_t)n0 * K + k0;
#pragma unroll
    for (int i = 0; i < 4; i++) {
      int cc = i * 256 + wave * 64 + lane;      // LDS 16B-slot id, 0..1023
      int r = cc >> 3;
      int c8 = (cc & 7) ^ (r & 7);              // swizzled source col chunk
      gll16(Ag + (size_t)r * K + c8 * 8, &Al[(i * 4 + wave) * 512]);
      gll16(Bg + (size_t)r * K + c8 * 8, &Bl[(i * 4 + wave) * 512]);
    }
    __syncthreads();
#pragma unroll
    for (int kc = 0; kc < 2; kc++) {
      // swizzled col offset: row&7 == l15&7 for all mi/ni (offsets are *8)
      const int csw = (((kc * 4 + quad) ^ (l15 & 7)) * 8);
      short8 af[4], bfr[4];
#pragma unroll
      for (int mi = 0; mi < 4; mi++)
        af[mi] = *(const short8*)&Al[(wm * 64 + mi * 16 + l15) * 64 + csw];
#pragma unroll
      for (int ni = 0; ni < 4; ni++)
        bfr[ni] = *(const short8*)&Bl[(wn * 64 + ni * 16 + l15) * 64 + csw];
#pragma unroll
      for (int mi = 0; mi < 4; mi++)
#pragma unroll
        for (int ni = 0; ni < 4; ni++)
          acc[mi][ni] = __builtin_amdgcn_mfma_f32_16x16x32_bf16(af[mi], bfr[ni], acc[mi][ni], 0, 0, 0);
    }
  }

  if constexpr (MODE == 0) {
#pragma unroll
    for (int mi = 0; mi < 4; mi++)
#pragma unroll
      for (int ni = 0; ni < 4; ni++) {
        int col = n0 + wn * 64 + ni * 16 + l15;
        float bv = bias[col];
#pragma unroll
        for (int r = 0; r < 4; r++) {
          int row = m0 + wm * 64 + mi * 16 + quad * 4 + r;
          Cout[(size_t)row * N + col] = acc[mi][ni][r] + bv;
        }
      }
  } else {
    int which = n0 >> 11;
    int h = (n0 >> 7) & 15;
    unsigned short* P = (which == 0) ? Qb : (which == 1) ? Kb : Vb;
#pragma unroll
    for (int mi = 0; mi < 4; mi++)
#pragma unroll
      for (int ni = 0; ni < 4; ni++) {
        int d = wn * 64 + ni * 16 + l15;
        float bv = bias[n0 + d];
#pragma unroll
        for (int r = 0; r < 4; r++) {
          int m = m0 + wm * 64 + mi * 16 + quad * 4 + r;
          int b = m >> 11, t = m & (T_ - 1);
          size_t addr = (which == 2)
              ? ((size_t)((b * H_ + h) * HD_ + d)) * T_ + t    // V transposed
              : ((size_t)((b * H_ + h) * T_ + t)) * HD_ + d;   // Q,K row-major
          P[addr] = f2bf(acc[mi][ni][r] + bv);
        }
      }
  }
}

// ---------------------------------------------------------------------------
// RoPE in-place on bf16 Q and K, layout [B*H*T][128].
// theta_p = 10000^(-(2**p)/128) (faithful 2**p quirk), pos 1-indexed,
// pair (d, d+64). Q pre-scaled by 1/sqrt(HD)*log2(e) for exp2 softmax.
// ---------------------------------------------------------------------------
__global__ void rope_k(unsigned short* __restrict__ Q, unsigned short* __restrict__ K)
{
  const int tid = threadIdx.x;
  const int w = tid >> 6, l = tid & 63;
  const int r = blockIdx.x * 4 + w;
  const int t = r & (T_ - 1);
  const float pos = (float)(t + 1);
  const float theta = expf(-exp2f((float)l) * 0.07195578415606394f); // ln(1e4)/128
  const float ang = pos * theta;
  const float c = cosf(ang), s = sinf(ang);
  const float QS = 0.08838834764831845f * 1.4426950408889634f; // 1/sqrt(128)*log2(e)
  const size_t base = (size_t)r * HD_;

  float q0 = bf2f(Q[base + l]), q1 = bf2f(Q[base + l + 64]);
  Q[base + l]      = f2bf((q0 * c - q1 * s) * QS);
  Q[base + l + 64] = f2bf((q1 * c + q0 * s) * QS);
  float k0 = bf2f(K[base + l]), k1 = bf2f(K[base + l + 64]);
  K[base + l]      = f2bf(k0 * c - k1 * s);
  K[base + l + 64] = f2bf(k1 * c + k0 * s);
}

// ---------------------------------------------------------------------------
// Flash-style causal attention (round-4 structure + XOR-swizzled K/V tiles).
// Grid 512 = (bh 32, XCD-swizzled) x (qpair 16); each block does Q-tiles
// qp*64 and (31-qp)*64 -> uniform 33 k-iters. 4 waves x 16 rows.
// Kl [64][128]: slot (r,c16) holds global (r, c16^(r&15)); read col-chunk
// (kc*4+quad)^l15. Vl [128][64]: slot (r,c8) holds (r, c8^(r&7)); read
// (kc*4+quad)^(l15&7). Both -> residual 2-way bank aliasing (free).
// ---------------------------------------------------------------------------
__global__ __launch_bounds__(256, 2)
void attn_k(const unsigned short* __restrict__ Q,
            const unsigned short* __restrict__ K,
            const unsigned short* __restrict__ Vt_g,
            unsigned short* __restrict__ AO)
{
  __shared__ unsigned short Kl[64 * 128];
  __shared__ unsigned short Vl[128 * 64];
  __shared__ unsigned short Pl[4 * 16 * 72];

  const int tid  = threadIdx.x;
  const int wave = tid >> 6, lane = tid & 63;
  const int quad = lane >> 4, l15 = lane & 15;
  const int blk = blockIdx.x;
  const int bh = (blk & 7) + 8 * ((blk >> 3) & 3);
  const int qp = (blk >> 5) & 15;
  const unsigned short* Qh = Q    + (size_t)bh * T_ * HD_;
  const unsigned short* Kh = K    + (size_t)bh * T_ * HD_;
  const unsigned short* Vh = Vt_g + (size_t)bh * T_ * HD_;  // [d][t]
  const int b = bh >> 4, h = bh & 15;

#pragma unroll
  for (int tile = 0; tile < 2; tile++) {
    const int q0 = (tile == 0 ? qp : 31 - qp) * 64;
    const int wq = q0 + wave * 16;
    short8 qf[4];
#pragma unroll
    for (int kc = 0; kc < 4; kc++)
      qf[kc] = *(const short8*)&Qh[(size_t)(wq + l15) * HD_ + kc * 32 + quad * 8];

    f32x4 oacc[8];
#pragma unroll
    for (int n = 0; n < 8; n++) oacc[n] = (f32x4){0.f, 0.f, 0.f, 0.f};
    float mst[4], lst[4];
#pragma unroll
    for (int r = 0; r < 4; r++) { mst[r] = -1e30f; lst[r] = 0.f; }

    const int niter = (q0 >> 6) + 1;
    for (int it = 0; it < niter; it++) {
      const int kt = it * 64;
      __syncthreads();
      // stage K [64][128] and V^T [128][64], source-col XOR swizzle
#pragma unroll
      for (int i = 0; i < 4; i++) {
        int cc = i * 256 + wave * 64 + lane;  // slot id 0..1023
        int kr = cc >> 4, kcs = (cc & 15) ^ (kr & 15);
        gll16(Kh + (size_t)(kt + kr) * HD_ + kcs * 8, &Kl[(i * 4 + wave) * 512]);
        int vr = cc >> 3, vcs = (cc & 7) ^ (vr & 7);
        gll16(Vh + (size_t)vr * T_ + kt + vcs * 8, &Vl[(i * 4 + wave) * 512]);
      }
      __syncthreads();

      // S' = (Q*s) K^T
      f32x4 sa[4];
#pragma unroll
      for (int ni = 0; ni < 4; ni++) sa[ni] = (f32x4){0.f, 0.f, 0.f, 0.f};
#pragma unroll
      for (int kc = 0; kc < 4; kc++) {
        const int cswK = (((kc * 4 + quad) ^ l15) * 8);
        short8 bfr[4];
#pragma unroll
        for (int ni = 0; ni < 4; ni++)
          bfr[ni] = *(const short8*)&Kl[(ni * 16 + l15) * HD_ + cswK];
#pragma unroll
        for (int ni = 0; ni < 4; ni++)
          sa[ni] = __builtin_amdgcn_mfma_f32_16x16x32_bf16(qf[kc], bfr[ni], sa[ni], 0, 0, 0);
      }

      if (kt == q0) {   // causal mask, diagonal tile only (uniform branch)
#pragma unroll
        for (int ni = 0; ni < 4; ni++) {
          int gcol = kt + ni * 16 + l15;
#pragma unroll
          for (int r = 0; r < 4; r++) {
            int grow = wq + quad * 4 + r;
            if (gcol > grow) sa[ni][r] = -1e30f;
          }
        }
      }

      // online softmax, base-2
      float rmax[4] = {-1e30f, -1e30f, -1e30f, -1e30f};
#pragma unroll
      for (int ni = 0; ni < 4; ni++)
#pragma unroll
        for (int r = 0; r < 4; r++) rmax[r] = fmaxf(rmax[r], sa[ni][r]);
#pragma unroll
      for (int r = 0; r < 4; r++)
#pragma unroll
        for (int off = 1; off < 16; off <<= 1)
          rmax[r] = fmaxf(rmax[r], __shfl_xor(rmax[r], off));
      float alpha[4];
#pragma unroll
      for (int r = 0; r < 4; r++) {
        float mnew = fmaxf(mst[r], rmax[r]);
        alpha[r] = fexp2(fminf(mst[r] - mnew, 0.f));
        mst[r] = mnew;
      }
      float rsum[4] = {0.f, 0.f, 0.f, 0.f};
#pragma unroll
      for (int ni = 0; ni < 4; ni++)
#pragma unroll
        for (int r = 0; r < 4; r++) {
          float p = fexp2(fminf(sa[ni][r] - mst[r], 0.f));
          sa[ni][r] = p;
          rsum[r] += p;
        }
#pragma unroll
      for (int r = 0; r < 4; r++) {
#pragma unroll
        for (int off = 1; off < 16; off <<= 1)
          rsum[r] += __shfl_xor(rsum[r], off);
        lst[r] = lst[r] * alpha[r] + rsum[r];
      }
#pragma unroll
      for (int nv = 0; nv < 8; nv++)
#pragma unroll
        for (int r = 0; r < 4; r++) oacc[nv][r] *= alpha[r];
#pragma unroll
      for (int ni = 0; ni < 4; ni++)
#pragma unroll
        for (int r = 0; r < 4; r++)
          Pl[wave * 16 * 72 + (quad * 4 + r) * 72 + ni * 16 + l15] = f2bf(sa[ni][r]);
      __syncthreads();

      // O += P V
      short8 pf[2];
#pragma unroll
      for (int kc = 0; kc < 2; kc++)
        pf[kc] = *(const short8*)&Pl[wave * 16 * 72 + l15 * 72 + kc * 32 + quad * 8];
#pragma unroll
      for (int kc = 0; kc < 2; kc++) {
        const int cswV = (((kc * 4 + quad) ^ (l15 & 7)) * 8);
#pragma unroll
        for (int nv = 0; nv < 8; nv++) {
          short8 vb = *(const short8*)&Vl[(nv * 16 + l15) * 64 + cswV];
          oacc[nv] = __builtin_amdgcn_mfma_f32_16x16x32_bf16(pf[kc], vb, oacc[nv], 0, 0, 0);
        }
      }
    }

    float linv[4];
#pragma unroll
    for (int r = 0; r < 4; r++) linv[r] = 1.0f / fmaxf(lst[r], 1e-20f);
#pragma unroll
    for (int nv = 0; nv < 8; nv++)
#pragma unroll
      for (int r = 0; r < 4; r++) {
        int t = wq + quad * 4 + r;
        int d = nv * 16 + l15;
        AO[((size_t)(b * T_ + t)) * C_ + h * HD_ + d] = f2bf(oacc[nv][r] * linv[r]);
      }
  }
}

// ---------------------------------------------------------------------------
// Fallback GEMM (f32 sources converted during staging) — only if ws too small.
// ---------------------------------------------------------------------------
template<int A32, int B32, int MODE>
__global__ __launch_bounds__(256, 2)
void gemm_nt(const void* __restrict__ Ap, const void* __restrict__ Bp,
             const float* __restrict__ bias,
             float* __restrict__ Cout,
             unsigned short* __restrict__ Qb,
             unsigned short* __restrict__ Kb,
             unsigned short* __restrict__ Vb,
             int N, int K)
{
  __shared__ unsigned short Al[128 * 72];
  __shared__ unsigned short Bl[128 * 72];
  const int tid  = threadIdx.x;
  const int wave = tid >> 6, lane = tid & 63;
  const int quad = lane >> 4, l15 = lane & 15;
  const int wm = wave >> 1, wn = wave & 1;
  const int n0 = blockIdx.x * 128, m0 = blockIdx.y * 128;

  f32x4 acc[4][4];
#pragma unroll
  for (int i = 0; i < 4; i++)
#pragma unroll
    for (int j = 0; j < 4; j++) acc[i][j] = (f32x4){0.f, 0.f, 0.f, 0.f};

  for (int k0 = 0; k0 < K; k0 += 64) {
    __syncthreads();
    if constexpr (A32) {
      const float* A = (const float*)Ap;
#pragma unroll
      for (int i = 0; i < 8; i++) {
        int cid = tid + i * 256;
        int r = cid >> 4, c = cid & 15;
        float4 v = *(const float4*)&A[(size_t)(m0 + r) * K + k0 + c * 4];
        ushort4 hh;
        hh.x = f2bf(v.x); hh.y = f2bf(v.y); hh.z = f2bf(v.z); hh.w = f2bf(v.w);
        *(ushort4*)&Al[r * 72 + c * 4] = hh;
      }
    } else {
      const unsigned short* A = (const unsigned short*)Ap;
#pragma unroll
      for (int i = 0; i < 4; i++) {
        int cid = tid + i * 256;
        int r = cid >> 3, c = cid & 7;
        *(float4*)&Al[r * 72 + c * 8] =
            *(const float4*)&A[(size_t)(m0 + r) * K + k0 + c * 8];
      }
    }
    if constexpr (B32) {
      const float* Bm = (const float*)Bp;
#pragma unroll
      for (int i = 0; i < 8; i++) {
        int cid = tid + i * 256;
        int r = cid >> 4, c = cid & 15;
        float4 v = *(const float4*)&Bm[(size_t)(n0 + r) * K + k0 + c * 4];
        ushort4 hh;
        hh.x = f2bf(v.x); hh.y = f2bf(v.y); hh.z = f2bf(v.z); hh.w = f2bf(v.w);
        *(ushort4*)&Bl[r * 72 + c * 4] = hh;
      }
    } else {
      const unsigned short* Bm = (const unsigned short*)Bp;
#pragma unroll
      for (int i = 0; i < 4; i++) {
        int cid = tid + i * 256;
        int r = cid >> 3, c = cid & 7;
        *(float4*)&Bl[r * 72 + c * 8] =
            *(const float4*)&Bm[(size_t)(n0 + r) * K + k0 + c * 8];
      }
    }
    __syncthreads();
#pragma unroll
    for (int kc = 0; kc < 2; kc++) {
      short8 af[4], bfr[4];
#pragma unroll
      for (int mi = 0; mi < 4; mi++)
        af[mi] = *(const short8*)&Al[(wm * 64 + mi * 16 + l15) * 72 + kc * 32 + quad * 8];
#pragma unroll
      for (int ni = 0; ni < 4; ni++)
        bfr[ni] = *(const short8*)&Bl[(wn * 64 + ni * 16 + l15) * 72 + kc * 32 + quad * 8];
#pragma unroll
      for (int mi = 0; mi < 4; mi++)
#pragma unroll
        for (int ni = 0; ni < 4; ni++)
          acc[mi][ni] = __builtin_amdgcn_mfma_f32_16x16x32_bf16(af[mi], bfr[ni], acc[mi][ni], 0, 0, 0);
    }
  }

  if constexpr (MODE == 0) {
#pragma unroll
    for (int mi = 0; mi < 4; mi++)
#pragma unroll
      for (int ni = 0; ni < 4; ni++) {
        int col = n0 + wn * 64 + ni * 16 + l15;
        float bv = bias[col];
#pragma unroll
        for (int r = 0; r < 4; r++) {
          int row = m0 + wm * 64 + mi * 16 + quad * 4 + r;
          Cout[(size_t)row * N + col] = acc[mi][ni][r] + bv;
        }
      }
  } else {
    int which = n0 >> 11;
    int h = (n0 >> 7) & 15;
    unsigned short* P = (which == 0) ? Qb : (which == 1) ? Kb : Vb;
#pragma unroll
    for (int mi = 0; mi < 4; mi++)
#pragma unroll
      for (int ni = 0; ni < 4; ni++) {
        int d = wn * 64 + ni * 16 + l15;
        float bv = bias[n0 + d];
#pragma unroll
        for (int r = 0; r < 4; r++) {
          int m = m0 + wm * 64 + mi * 16 + quad * 4 + r;
          int b = m >> 11, t = m & (T_ - 1);
          size_t addr = (which == 2)
              ? ((size_t)((b * H_ + h) * HD_ + d)) * T_ + t
              : ((size_t)((b * H_ + h) * T_ + t)) * HD_ + d;
          P[addr] = f2bf(acc[mi][ni][r] + bv);
        }
      }
  }
}

// ---------------------------------------------------------------------------
extern "C" void kernel_launch(void* const* d_in, const int* in_sizes, int n_in,
                              void* d_out, int out_size, void* d_ws, size_t ws_size,
                              hipStream_t stream)
{
  const float* x    = (const float*)d_in[0];  // [2,2048,2048] f32
  const float* Wqkv = (const float*)d_in[1];  // [6144,2048]   f32
  const float* bqkv = (const float*)d_in[2];  // [6144]        f32
  const float* Wo   = (const float*)d_in[3];  // [2048,2048]   f32
  const float* bo   = (const float*)d_in[4];  // [2048]        f32
  float* out = (float*)d_out;                 // [2,2048,2048] f32

  const size_t SZ   = (size_t)B_ * H_ * T_ * HD_;   // 8,388,608
  const size_t NX   = SZ;
  const size_t NWQ  = (size_t)3 * C_ * C_;
  const size_t NWO  = (size_t)C_ * C_;
  unsigned short* ws = (unsigned short*)d_ws;

  dim3 blk(256, 1, 1);
  const size_t need = (NX + NWQ + 3 * SZ) * sizeof(unsigned short);  // 92.3 MB

  if (ws_size >= need) {
    unsigned short* xb    = ws;
    unsigned short* Wqkvb = xb + NX;
    unsigned short* Qb    = Wqkvb + NWQ;
    unsigned short* Kb    = Qb + SZ;
    unsigned short* Vb    = Kb + SZ;      // transposed [bh][d][t]
    unsigned short* AO    = xb;           // alias: x dead after QKV GEMM
    unsigned short* Wob   = Wqkvb;        // alias: Wqkv dead after QKV GEMM

    cvt_k<<<dim3((unsigned)(NX / 1024)), blk, 0, stream>>>(x, xb, (int)(NX / 4));
    cvt_k<<<dim3((unsigned)(NWQ / 1024)), blk, 0, stream>>>(Wqkv, Wqkvb, (int)(NWQ / 4));
    gemm_bt<1><<<dim3(48, 32, 1), blk, 0, stream>>>(
        xb, Wqkvb, bqkv, nullptr, Qb, Kb, Vb, 6144, 2048);
    cvt_k<<<dim3((unsigned)(NWO / 1024)), blk, 0, stream>>>(Wo, Wob, (int)(NWO / 4));
    rope_k<<<dim3((B_ * H_ * T_) / 4, 1, 1), blk, 0, stream>>>(Qb, Kb);
    attn_k<<<dim3(512, 1, 1), blk, 0, stream>>>(Qb, Kb, Vb, AO);
    gemm_bt<0><<<dim3(16, 32, 1), blk, 0, stream>>>(
        AO, Wob, bo, out, nullptr, nullptr, nullptr, 2048, 2048);
  } else {
    unsigned short* Qb = ws;
    unsigned short* Kb = Qb + SZ;
    unsigned short* Vb = Kb + SZ;
    unsigned short* AO = Vb + SZ;
    gemm_nt<1, 1, 1><<<dim3(48, 32, 1), blk, 0, stream>>>(
        (const void*)x, (const void*)Wqkv, bqkv, nullptr, Qb, Kb, Vb, 6144, 2048);
    rope_k<<<dim3((B_ * H_ * T_) / 4, 1, 1), blk, 0, stream>>>(Qb, Kb);
    attn_k<<<dim3(512, 1, 1), blk, 0, stream>>>(Qb, Kb, Vb, AO);
    gemm_nt<0, 1, 0><<<dim3(16, 32, 1), blk, 0, stream>>>(
        (const void*)AO, (const void*)Wo, bo, out, nullptr, nullptr, nullptr, 2048, 2048);
  }
}